// Round 5
// baseline (66.538 us; speedup 1.0000x reference)
//
#include <hip/hip_runtime.h>

// PathBundleChoiceScorer — reduced computation (verified rounds 1-4):
//   t1 = tanh(x @ W1^T); t2 = tanh(t1 @ W2^T); s[n] = dot(t2[n,:], Wout)
//   out[n] = top9-weighted collapse of {c_j*s}, c fixed {-1,0,+1} pattern.
// Round 5: occupancy fix — BM=64 x BN=128 tiles, 2-wave blocks, 512 blocks
// (2 blocks/CU, independent barrier domains overlap). Triple-buffered LDS,
// counted vmcnt(12) (stage t+2, never drain in-loop), 8-slot XOR swizzle,
// bijective XCD block swizzle. fp16 single-product MFMA (round-4 numerics).

typedef __attribute__((ext_vector_type(4))) float     f32x4;
typedef __attribute__((ext_vector_type(8))) _Float16  f16x8;

#define AS1 __attribute__((address_space(1)))
#define AS3 __attribute__((address_space(3)))
#define GLOAD16(gp, lp) \
    __builtin_amdgcn_global_load_lds((AS1 const void*)(gp), (AS3 void*)(lp), 16, 0, 0)

// ---- f32 -> f16 convert: x (4M elems), W1 (1M), W2 (1M); 8 elems/thread ----
__global__ __launch_bounds__(256)
void pbcs_cvt(const float* __restrict__ x,  _Float16* __restrict__ xo,
              const float* __restrict__ w1, _Float16* __restrict__ w1o,
              const float* __restrict__ w2, _Float16* __restrict__ w2o)
{
    const int b = blockIdx.x;
    const float* src; _Float16* dst; int idx;
    if (b < 2048)      { src = x;  dst = xo;  idx = b * 256 + threadIdx.x; }
    else if (b < 2560) { src = w1; dst = w1o; idx = (b - 2048) * 256 + threadIdx.x; }
    else               { src = w2; dst = w2o; idx = (b - 2560) * 256 + threadIdx.x; }
    const float4 v0 = ((const float4*)src)[idx * 2];
    const float4 v1 = ((const float4*)src)[idx * 2 + 1];
    f16x8 h;
    h[0] = (_Float16)v0.x; h[1] = (_Float16)v0.y;
    h[2] = (_Float16)v0.z; h[3] = (_Float16)v0.w;
    h[4] = (_Float16)v1.x; h[5] = (_Float16)v1.y;
    h[6] = (_Float16)v1.z; h[7] = (_Float16)v1.w;
    ((f16x8*)dst)[idx] = h;
}

// ---- fp16 MFMA GEMM:  C = A @ B^T, A [4096,1024] f16, B [1024,1024] f16 ----
// 128 threads = 2 waves, block tile 64x128, wave tile 64x64, BK=64, 16 k-tiles.
// Triple-buffered (stage t+2, wait vmcnt(12)).
// EPI=0: Cout = tanh(acc) f16.  EPI=1: s_part fused wout dot.
template<int EPI>
__global__ __launch_bounds__(128)
void pbcs_gemm16(const _Float16* __restrict__ A, const _Float16* __restrict__ B,
                 _Float16* __restrict__ Cout, const float* __restrict__ wout,
                 float* __restrict__ s_part)
{
    __shared__ char smem[3][24576];   // [buf][ A 8K | B 16K ]

    const int tid  = threadIdx.x;
    const int lane = tid & 63;
    const int wid  = tid >> 6;        // 0..1 (wave); also wn (col half)
    const int l15  = lane & 15;
    const int g    = lane >> 4;       // k-group 0..3

    // bijective XCD swizzle: 512 blocks, XCD (= b&7) owns 64 consecutive ids
    const int b  = blockIdx.x;
    const int id = (b & 7) * 64 + (b >> 3);
    const int bm = id >> 3;           // 0..63  (64-row stripe)
    const int bn = id & 7;            // 0..7   (128-col stripe)

    // ---- staging: 24 chunks of 1KB (8 A + 16 B), 12 per wave, interleaved ----
    // chunk rows: 8 x 128B; lane r = lane>>3 (row), s = lane&7 (16B slot);
    // pre-swizzled source: slot s holds k-slot s^r  (read undoes it).
    const int r = lane >> 3, s = lane & 7;
    const char* aBase = (const char*)A
        + (size_t)(bm * 64 + wid * 8 + r) * 2048 + 16 * (s ^ r);
    const char* bBase = (const char*)B
        + (size_t)(bn * 128 + wid * 8 + r) * 2048 + 16 * (s ^ r);

#define STAGE(buf, kt) do {                                                   \
        const int _ko = (kt) * 128;                                           \
        _Pragma("unroll")                                                     \
        for (int _j = 0; _j < 4; ++_j)      /* A chunks c = 2j+wid */         \
            GLOAD16(aBase + _j * (16 * 2048) + _ko,                           \
                    smem[buf] + (2 * _j + wid) * 1024);                       \
        _Pragma("unroll")                                                     \
        for (int _j = 0; _j < 8; ++_j)      /* B chunks c = 2j+wid */         \
            GLOAD16(bBase + _j * (16 * 2048) + _ko,                           \
                    smem[buf] + 8192 + (2 * _j + wid) * 1024);                \
    } while (0)

    // ---- LDS read offsets (swizzle-undo) ----
    int aoff[4][2], boff[4][2];
#pragma unroll
    for (int f = 0; f < 4; ++f) {
        const int ra = f * 16 + l15;              // A row 0..63
        const int rb = wid * 64 + f * 16 + l15;   // B row (col of C)
#pragma unroll
        for (int kh = 0; kh < 2; ++kh) {
            aoff[f][kh] = ra * 128 + 16 * (((kh << 2) | g) ^ (ra & 7));
            boff[f][kh] = 8192 + rb * 128 + 16 * (((kh << 2) | g) ^ (rb & 7));
        }
    }

    f32x4 acc[4][4];
#pragma unroll
    for (int i = 0; i < 4; ++i)
#pragma unroll
        for (int j = 0; j < 4; ++j) acc[i][j] = (f32x4)0.f;

#define COMPUTE(buf) do {                                                        \
        _Pragma("unroll")                                                        \
        for (int _kh = 0; _kh < 2; ++_kh) {                                      \
            f16x8 _a[4], _b[4];                                                  \
            _Pragma("unroll")                                                    \
            for (int _f = 0; _f < 4; ++_f) {                                     \
                _a[_f] = *(const f16x8*)(smem[buf] + aoff[_f][_kh]);             \
                _b[_f] = *(const f16x8*)(smem[buf] + boff[_f][_kh]);             \
            }                                                                    \
            _Pragma("unroll")                                                    \
            for (int _mf = 0; _mf < 4; ++_mf)                                    \
            _Pragma("unroll")                                                    \
            for (int _nf = 0; _nf < 4; ++_nf)                                    \
                acc[_mf][_nf] = __builtin_amdgcn_mfma_f32_16x16x32_f16(          \
                    _a[_mf], _b[_nf], acc[_mf][_nf], 0, 0, 0);                   \
        }                                                                        \
    } while (0)

    // ---- triple-buffered counted-vmcnt loop over 16 k-tiles ----
    STAGE(0, 0);
    STAGE(1, 1);
    int cb = 0, sb = 2;
#pragma unroll 1
    for (int t = 0; t < 15; ++t) {
        asm volatile("s_waitcnt vmcnt(12)" ::: "memory");  // tile t landed
        __builtin_amdgcn_s_barrier();
        __builtin_amdgcn_sched_barrier(0);
        COMPUTE(cb);
        asm volatile("s_waitcnt lgkmcnt(0)" ::: "memory");
        __builtin_amdgcn_sched_barrier(0);
        __builtin_amdgcn_s_barrier();                      // both waves done reading
        if (t < 14) STAGE(sb, t + 2);
        cb = (cb == 2) ? 0 : cb + 1;
        sb = (sb == 2) ? 0 : sb + 1;
    }
    asm volatile("s_waitcnt vmcnt(0)" ::: "memory");
    __builtin_amdgcn_s_barrier();
    __builtin_amdgcn_sched_barrier(0);
    COMPUTE(0);   // t = 15 (15 % 3 == 0)

    // ---- epilogue ----
    if (EPI == 0) {
#pragma unroll
        for (int mf = 0; mf < 4; ++mf)
#pragma unroll
        for (int nf = 0; nf < 4; ++nf)
#pragma unroll
        for (int jj = 0; jj < 4; ++jj) {
            const int row = bm * 64 + mf * 16 + g * 4 + jj;
            const int col = bn * 128 + wid * 64 + nf * 16 + l15;
            Cout[(size_t)row * 1024 + col] = (_Float16)tanhf(acc[mf][nf][jj]);
        }
    } else {
        float w[4];
#pragma unroll
        for (int nf = 0; nf < 4; ++nf)
            w[nf] = wout[bn * 128 + wid * 64 + nf * 16 + l15];
#pragma unroll
        for (int mf = 0; mf < 4; ++mf)
#pragma unroll
        for (int jj = 0; jj < 4; ++jj) {
            float v = 0.f;
#pragma unroll
            for (int nf = 0; nf < 4; ++nf)
                v += tanhf(acc[mf][nf][jj]) * w[nf];
            v += __shfl_xor(v, 1, 64);
            v += __shfl_xor(v, 2, 64);
            v += __shfl_xor(v, 4, 64);
            v += __shfl_xor(v, 8, 64);
            if (l15 == 0) {
                const int row = bm * 64 + mf * 16 + g * 4 + jj;
                s_part[row * 16 + bn * 2 + wid] = v;
            }
        }
    }
#undef STAGE
#undef COMPUTE
}

// ---- finalize: s = sum(s_part), then faithful 27-path top-9 collapse -------
__global__ __launch_bounds__(256)
void pbcs_finalize(const float* __restrict__ s_part,
                   const float* __restrict__ soa_w, const float* __restrict__ soa_b,
                   const float* __restrict__ sob_w, const float* __restrict__ sob_b,
                   float* __restrict__ out, int Nrows)
{
    const int row  = blockIdx.x * 4 + (threadIdx.x >> 6);
    const int lane = threadIdx.x & 63;
    if (row >= Nrows) return;

    float part = (lane < 16) ? s_part[row * 16 + lane] : 0.f;
#pragma unroll
    for (int off = 32; off > 0; off >>= 1) part += __shfl_xor(part, off, 64);
    const float s = part;

    const float C7 = 0.8975979010256552f;   // 2*pi/7
    float tS = 0.f, tZ = 0.f, tN = 0.f;
    if (lane < 32) {
        const float aw = soa_w[lane];
        const float ab = soa_b[lane];
        const float bw = sob_w[lane];
        tS = bw * sinf(C7 * fmaf(aw,  s, ab));
        tZ = bw * sinf(C7 * ab);
        tN = bw * sinf(C7 * fmaf(aw, -s, ab));
    }
#pragma unroll
    for (int off = 32; off > 0; off >>= 1) {
        tS += __shfl_xor(tS, off, 64);
        tZ += __shfl_xor(tZ, off, 64);
        tN += __shfl_xor(tN, off, 64);
    }
    const float bb = sob_b[0];
    const float fS = tS + bb;
    const float f0 = tZ + bb;
    const float fN = tN + bb;

    // 27 paths: P[k] = {1,0,-1,0,0,0,-1,0,1}; tri q: (-pos, 0, +pos)
    const int j  = lane;
    const int kk = j / 3;
    const int q  = j - kk * 3;
    const int p  = ((0x101 >> kk) & 1) - ((0x044 >> kk) & 1);
    const int c  = (q == 0) ? -p : ((q == 2) ? p : 0);
    const float val = (float)c * s;
    const float sc  = (c == 0) ? f0 : ((c > 0) ? fS : fN);

    int rank = 0;
#pragma unroll 1
    for (int i = 0; i < 27; ++i) {
        const float sci = __shfl(sc, i, 64);
        rank += (sci > sc) || (sci == sc && i < j);
    }
    const float mx = fmaxf(fS, fmaxf(f0, fN));
    float e = (j < 27 && rank < 9) ? expf(sc - mx) : 0.f;
    float num = val * e;
    float den = e;
#pragma unroll
    for (int off = 32; off > 0; off >>= 1) {
        num += __shfl_xor(num, off, 64);
        den += __shfl_xor(den, off, 64);
    }
    if (lane == 0) out[row] = num / den;
}

extern "C" void kernel_launch(void* const* d_in, const int* in_sizes, int n_in,
                              void* d_out, int out_size, void* d_ws, size_t ws_size,
                              hipStream_t stream)
{
    const float* x     = (const float*)d_in[0];
    const float* W1    = (const float*)d_in[1];
    const float* W2    = (const float*)d_in[2];
    const float* Wout  = (const float*)d_in[3];
    const float* soa_w = (const float*)d_in[12];
    const float* soa_b = (const float*)d_in[13];
    const float* sob_w = (const float*)d_in[14];
    const float* sob_b = (const float*)d_in[15];

    const int Nr = 4096;
    char* ws = (char*)d_ws;
    _Float16* xf  = (_Float16*)ws;                    //  8MB  [4096,1024]
    _Float16* t1f = (_Float16*)(ws + (8u  << 20));    //  8MB  [4096,1024]
    _Float16* w1f = (_Float16*)(ws + (16u << 20));    //  2MB  [1024,1024]
    _Float16* w2f = (_Float16*)(ws + (18u << 20));    //  2MB  [1024,1024]
    float* s_part = (float*)(ws + (20u << 20));       //  256KB

    pbcs_cvt<<<3072, 256, 0, stream>>>(x, xf, W1, w1f, W2, w2f);

    pbcs_gemm16<0><<<512, 128, 0, stream>>>(xf,  w1f, t1f, nullptr, nullptr);
    pbcs_gemm16<1><<<512, 128, 0, stream>>>(t1f, w2f, nullptr, Wout, s_part);

    pbcs_finalize<<<Nr / 4, 256, 0, stream>>>(s_part, soa_w, soa_b, sob_w, sob_b,
                                              (float*)d_out, Nr);
}

// Round 6
// 56.633 us; speedup vs baseline: 1.1749x; 1.1749x over previous
//
#include <hip/hip_runtime.h>

// PathBundleChoiceScorer — reduced computation (verified rounds 1-5):
//   t1 = tanh(x @ W1^T); t2 = tanh(t1 @ W2^T); s[n] = dot(t2[n,:], Wout)
//   out[n] = top9-weighted collapse of {c_j*s}, c fixed {-1,0,+1} pattern.
// Round 6: in-block split-K. 512-thread blocks (8 waves = 2/SIMD), tile
// 128x128, waves (wk,wm,wn) 2x2x2, each wave 64x64 over its K-half (512).
// Round-4 swizzle/compute per half (BK=64, counted vmcnt(8)), 128KB dynamic
// LDS double-buffered, LDS k-reduce epilogue. fp16 single-product MFMA.

typedef __attribute__((ext_vector_type(4))) float     f32x4;
typedef __attribute__((ext_vector_type(8))) _Float16  f16x8;

#define AS1 __attribute__((address_space(1)))
#define AS3 __attribute__((address_space(3)))
#define GLOAD16(gp, lp) \
    __builtin_amdgcn_global_load_lds((AS1 const void*)(gp), (AS3 void*)(lp), 16, 0, 0)

// ---- f32 -> f16 convert: x (4M elems), W1 (1M), W2 (1M); 8 elems/thread ----
__global__ __launch_bounds__(256)
void pbcs_cvt(const float* __restrict__ x,  _Float16* __restrict__ xo,
              const float* __restrict__ w1, _Float16* __restrict__ w1o,
              const float* __restrict__ w2, _Float16* __restrict__ w2o)
{
    const int b = blockIdx.x;
    const float* src; _Float16* dst; int idx;
    if (b < 2048)      { src = x;  dst = xo;  idx = b * 256 + threadIdx.x; }
    else if (b < 2560) { src = w1; dst = w1o; idx = (b - 2048) * 256 + threadIdx.x; }
    else               { src = w2; dst = w2o; idx = (b - 2560) * 256 + threadIdx.x; }
    const float4 v0 = ((const float4*)src)[idx * 2];
    const float4 v1 = ((const float4*)src)[idx * 2 + 1];
    f16x8 h;
    h[0] = (_Float16)v0.x; h[1] = (_Float16)v0.y;
    h[2] = (_Float16)v0.z; h[3] = (_Float16)v0.w;
    h[4] = (_Float16)v1.x; h[5] = (_Float16)v1.y;
    h[6] = (_Float16)v1.z; h[7] = (_Float16)v1.w;
    ((f16x8*)dst)[idx] = h;
}

// ---- fp16 MFMA GEMM, in-block split-K ---------------------------------------
// A [4096,1024] f16, B [1024,1024] f16 (row-major, C = A @ B^T).
// 512 threads = 8 waves: wk=wid>>2, wm=(wid>>1)&1, wn=wid&1.
// Wave tile 64x64 over K-half 512 (8 k-tiles of 64). LDS k-reduce at end.
// EPI=0: Cout = tanh(acc) f16.  EPI=1: s_part fused wout dot.
template<int EPI>
__global__ __launch_bounds__(512, 1)
void pbcs_gemm16(const _Float16* __restrict__ A, const _Float16* __restrict__ B,
                 _Float16* __restrict__ Cout, const float* __restrict__ wout,
                 float* __restrict__ s_part)
{
    extern __shared__ char smem[];    // 2 x 64KB: [A0 16K|B0 16K|A1 16K|B1 16K]

    const int tid  = threadIdx.x;
    const int lane = tid & 63;
    const int wid  = tid >> 6;        // 0..7
    const int wk   = wid >> 2;        // k-half
    const int wm   = (wid >> 1) & 1;  // row half
    const int wn   = wid & 1;         // col half
    const int l15  = lane & 15;
    const int g    = lane >> 4;       // k-group 0..3

    // bijective XCD swizzle (round-4): XCD owns 4 bm-stripes x all bn
    const int b  = blockIdx.x;                     // 0..255
    const int bm = (b & 7) * 4 + ((b >> 3) & 3);   // 0..31
    const int bn = b >> 5;                         // 0..7

    // ---- staging: 64 chunks of 1KB/iter, 8 per wave; wave covers its own
    // k-half h=wk; (wid>>1)&1 -> A/B... mapping: c = wid*8+j ->
    // h=c>>5 (=wk), mat=(c>>4)&1, cc=c&15 = (wid&1)*8+j.
    const int r = lane >> 3, sslot = lane & 7;     // chunk row, 16B slot
    const int isB = (wid >> 1) & 1;
    const char* stageSrc[8]; int stageDst[8];
#pragma unroll
    for (int j = 0; j < 8; ++j) {
        const int cc  = (wid & 1) * 8 + j;
        const int row = (isB ? bn : bm) * 128 + cc * 8 + r;
        const char* base = (const char*)(isB ? B : A);
        stageSrc[j] = base + (size_t)row * 2048 + wk * 1024 + 16 * (sslot ^ r);
        stageDst[j] = wk * 32768 + isB * 16384 + cc * 1024;
    }

#define STAGE(buf, kt) do {                                              \
        const int _ko = (kt) * 128;                                      \
        _Pragma("unroll")                                                \
        for (int _j = 0; _j < 8; ++_j)                                   \
            GLOAD16(stageSrc[_j] + _ko,                                  \
                    smem + (buf) * 65536 + stageDst[_j]);                \
    } while (0)

    // ---- LDS read offsets (swizzle-undo), relative to the wave's half ----
    int aoff[4][2], boff[4][2];
#pragma unroll
    for (int f = 0; f < 4; ++f) {
        const int ra = wm * 64 + f * 16 + l15;
        const int rb = wn * 64 + f * 16 + l15;
#pragma unroll
        for (int kh = 0; kh < 2; ++kh) {
            aoff[f][kh] = ra * 128 + 16 * (((kh << 2) | g) ^ (ra & 7));
            boff[f][kh] = 16384 + rb * 128 + 16 * (((kh << 2) | g) ^ (rb & 7));
        }
    }

    f32x4 acc[4][4];
#pragma unroll
    for (int i = 0; i < 4; ++i)
#pragma unroll
        for (int j = 0; j < 4; ++j) acc[i][j] = (f32x4)0.f;

#define COMPUTE(buf) do {                                                        \
        const char* _L = smem + (buf) * 65536 + wk * 32768;                      \
        _Pragma("unroll")                                                        \
        for (int _kh = 0; _kh < 2; ++_kh) {                                      \
            f16x8 _a[4], _b[4];                                                  \
            _Pragma("unroll")                                                    \
            for (int _f = 0; _f < 4; ++_f) {                                     \
                _a[_f] = *(const f16x8*)(_L + aoff[_f][_kh]);                    \
                _b[_f] = *(const f16x8*)(_L + boff[_f][_kh]);                    \
            }                                                                    \
            _Pragma("unroll")                                                    \
            for (int _mf = 0; _mf < 4; ++_mf)                                    \
            _Pragma("unroll")                                                    \
            for (int _nf = 0; _nf < 4; ++_nf)                                    \
                acc[_mf][_nf] = __builtin_amdgcn_mfma_f32_16x16x32_f16(          \
                    _a[_mf], _b[_nf], acc[_mf][_nf], 0, 0, 0);                   \
        }                                                                        \
    } while (0)

    // ---- double-buffered counted-vmcnt loop: 8 k-tiles per half ----
    STAGE(0, 0);
    STAGE(1, 1);
#pragma unroll 1
    for (int t = 0; t < 8; ++t) {
        if (t < 7) { asm volatile("s_waitcnt vmcnt(8)" ::: "memory"); }
        else       { asm volatile("s_waitcnt vmcnt(0)" ::: "memory"); }
        __builtin_amdgcn_s_barrier();
        __builtin_amdgcn_sched_barrier(0);
        COMPUTE(t & 1);
        asm volatile("s_waitcnt lgkmcnt(0)" ::: "memory");
        __builtin_amdgcn_sched_barrier(0);
        __builtin_amdgcn_s_barrier();
        if (t < 6) STAGE(t & 1, t + 2);
    }

    // ---- k-reduce: wk=1 waves publish, wk=0 waves accumulate ----
    const int pair = wm * 2 + wn;
    if (wk == 1) {
#pragma unroll
        for (int mf = 0; mf < 4; ++mf)
#pragma unroll
        for (int nf = 0; nf < 4; ++nf)
            *(f32x4*)(smem + pair * 16384 + (mf * 4 + nf) * 1024 + lane * 16)
                = acc[mf][nf];
    }
    asm volatile("s_waitcnt lgkmcnt(0)" ::: "memory");
    __builtin_amdgcn_s_barrier();
    if (wk == 1) return;
#pragma unroll
    for (int mf = 0; mf < 4; ++mf)
#pragma unroll
    for (int nf = 0; nf < 4; ++nf)
        acc[mf][nf] += *(const f32x4*)(smem + pair * 16384
                                       + (mf * 4 + nf) * 1024 + lane * 16);

    // ---- epilogue (wk=0 waves only) ----
    if (EPI == 0) {
#pragma unroll
        for (int mf = 0; mf < 4; ++mf)
#pragma unroll
        for (int nf = 0; nf < 4; ++nf)
#pragma unroll
        for (int jj = 0; jj < 4; ++jj) {
            const int row = bm * 128 + wm * 64 + mf * 16 + g * 4 + jj;
            const int col = bn * 128 + wn * 64 + nf * 16 + l15;
            Cout[(size_t)row * 1024 + col] = (_Float16)tanhf(acc[mf][nf][jj]);
        }
    } else {
        float w[4];
#pragma unroll
        for (int nf = 0; nf < 4; ++nf)
            w[nf] = wout[bn * 128 + wn * 64 + nf * 16 + l15];
#pragma unroll
        for (int mf = 0; mf < 4; ++mf)
#pragma unroll
        for (int jj = 0; jj < 4; ++jj) {
            float v = 0.f;
#pragma unroll
            for (int nf = 0; nf < 4; ++nf)
                v += tanhf(acc[mf][nf][jj]) * w[nf];
            v += __shfl_xor(v, 1, 64);
            v += __shfl_xor(v, 2, 64);
            v += __shfl_xor(v, 4, 64);
            v += __shfl_xor(v, 8, 64);
            if (l15 == 0) {
                const int row = bm * 128 + wm * 64 + mf * 16 + g * 4 + jj;
                s_part[row * 16 + bn * 2 + wn] = v;
            }
        }
    }
#undef STAGE
#undef COMPUTE
}

// ---- finalize: s = sum(s_part), then faithful 27-path top-9 collapse -------
__global__ __launch_bounds__(256)
void pbcs_finalize(const float* __restrict__ s_part,
                   const float* __restrict__ soa_w, const float* __restrict__ soa_b,
                   const float* __restrict__ sob_w, const float* __restrict__ sob_b,
                   float* __restrict__ out, int Nrows)
{
    const int row  = blockIdx.x * 4 + (threadIdx.x >> 6);
    const int lane = threadIdx.x & 63;
    if (row >= Nrows) return;

    float part = (lane < 16) ? s_part[row * 16 + lane] : 0.f;
#pragma unroll
    for (int off = 32; off > 0; off >>= 1) part += __shfl_xor(part, off, 64);
    const float s = part;

    const float C7 = 0.8975979010256552f;   // 2*pi/7
    float tS = 0.f, tZ = 0.f, tN = 0.f;
    if (lane < 32) {
        const float aw = soa_w[lane];
        const float ab = soa_b[lane];
        const float bw = sob_w[lane];
        tS = bw * sinf(C7 * fmaf(aw,  s, ab));
        tZ = bw * sinf(C7 * ab);
        tN = bw * sinf(C7 * fmaf(aw, -s, ab));
    }
#pragma unroll
    for (int off = 32; off > 0; off >>= 1) {
        tS += __shfl_xor(tS, off, 64);
        tZ += __shfl_xor(tZ, off, 64);
        tN += __shfl_xor(tN, off, 64);
    }
    const float bb = sob_b[0];
    const float fS = tS + bb;
    const float f0 = tZ + bb;
    const float fN = tN + bb;

    // 27 paths: P[k] = {1,0,-1,0,0,0,-1,0,1}; tri q: (-pos, 0, +pos)
    const int j  = lane;
    const int kk = j / 3;
    const int q  = j - kk * 3;
    const int p  = ((0x101 >> kk) & 1) - ((0x044 >> kk) & 1);
    const int c  = (q == 0) ? -p : ((q == 2) ? p : 0);
    const float val = (float)c * s;
    const float sc  = (c == 0) ? f0 : ((c > 0) ? fS : fN);

    int rank = 0;
#pragma unroll 1
    for (int i = 0; i < 27; ++i) {
        const float sci = __shfl(sc, i, 64);
        rank += (sci > sc) || (sci == sc && i < j);
    }
    const float mx = fmaxf(fS, fmaxf(f0, fN));
    float e = (j < 27 && rank < 9) ? expf(sc - mx) : 0.f;
    float num = val * e;
    float den = e;
#pragma unroll
    for (int off = 32; off > 0; off >>= 1) {
        num += __shfl_xor(num, off, 64);
        den += __shfl_xor(den, off, 64);
    }
    if (lane == 0) out[row] = num / den;
}

extern "C" void kernel_launch(void* const* d_in, const int* in_sizes, int n_in,
                              void* d_out, int out_size, void* d_ws, size_t ws_size,
                              hipStream_t stream)
{
    const float* x     = (const float*)d_in[0];
    const float* W1    = (const float*)d_in[1];
    const float* W2    = (const float*)d_in[2];
    const float* Wout  = (const float*)d_in[3];
    const float* soa_w = (const float*)d_in[12];
    const float* soa_b = (const float*)d_in[13];
    const float* sob_w = (const float*)d_in[14];
    const float* sob_b = (const float*)d_in[15];

    const int Nr = 4096;
    char* ws = (char*)d_ws;
    _Float16* xf  = (_Float16*)ws;                    //  8MB  [4096,1024]
    _Float16* t1f = (_Float16*)(ws + (8u  << 20));    //  8MB  [4096,1024]
    _Float16* w1f = (_Float16*)(ws + (16u << 20));    //  2MB  [1024,1024]
    _Float16* w2f = (_Float16*)(ws + (18u << 20));    //  2MB  [1024,1024]
    float* s_part = (float*)(ws + (20u << 20));       //  256KB

    // allow 128KB dynamic LDS (host-side metadata; capture-safe)
    hipFuncSetAttribute((const void*)pbcs_gemm16<0>,
                        hipFuncAttributeMaxDynamicSharedMemorySize, 131072);
    hipFuncSetAttribute((const void*)pbcs_gemm16<1>,
                        hipFuncAttributeMaxDynamicSharedMemorySize, 131072);

    pbcs_cvt<<<3072, 256, 0, stream>>>(x, xf, W1, w1f, W2, w2f);

    pbcs_gemm16<0><<<256, 512, 131072, stream>>>(xf,  w1f, t1f, nullptr, nullptr);
    pbcs_gemm16<1><<<256, 512, 131072, stream>>>(t1f, w2f, nullptr, Wout, s_part);

    pbcs_finalize<<<Nr / 4, 256, 0, stream>>>(s_part, soa_w, soa_b, sob_w, sob_b,
                                              (float*)d_out, Nr);
}